// Round 1
// baseline (203.043 us; speedup 1.0000x reference)
//
#include <hip/hip_runtime.h>
#include <hip/hip_bf16.h>
#include <stdint.h>

// Problem dims (fixed by reference): h [8, 2048, 128] fp32 -> adj [8, 2048, 2048] fp32
#define NB 8
#define NN 2048
#define ND 128

typedef __attribute__((ext_vector_type(8))) short short8;   // 8 bf16 = 4 VGPR (MFMA A/B frag)
typedef __attribute__((ext_vector_type(4))) float f32x4;    // MFMA C/D frag

__device__ __forceinline__ uint32_t pack_bf16(float a, float b) {
    unsigned short ua = __builtin_bit_cast(unsigned short, __float2bfloat16(a));
    unsigned short ub = __builtin_bit_cast(unsigned short, __float2bfloat16(b));
    return (uint32_t)ua | ((uint32_t)ub << 16);
}
__device__ __forceinline__ float unpk_lo(uint32_t p) { return __builtin_bit_cast(float, p << 16); }
__device__ __forceinline__ float unpk_hi(uint32_t p) { return __builtin_bit_cast(float, p & 0xffff0000u); }

// Kernel 1: fp32 row-normalize -> bf16 hn in workspace.
// One wave per row (64 lanes x 2 floats = 128 = D), 4 waves per block.
__global__ __launch_bounds__(256) void adjnorm_kernel(const float* __restrict__ h,
                                                      unsigned short* __restrict__ hn) {
    const int row  = blockIdx.x * 4 + (threadIdx.x >> 6);
    const int lane = threadIdx.x & 63;
    const float2 v = reinterpret_cast<const float2*>(h + (size_t)row * ND)[lane];
    float ss = v.x * v.x + v.y * v.y;
    #pragma unroll
    for (int m = 32; m >= 1; m >>= 1) ss += __shfl_xor(ss, m);
    const float nrm = fmaxf(sqrtf(ss), 1e-8f);   // torch cosine_similarity eps
    const float inv = 1.0f / nrm;
    reinterpret_cast<uint32_t*>(hn + (size_t)row * ND)[lane] = pack_bf16(v.x * inv, v.y * inv);
}

// Kernel 2: fused sim-GEMM + softmax.
// Block = 8 waves = 512 thr, owns 32 rows x 2048 cols of one batch.
// Wave (rh = wid>>2, cq = wid&3): 16 rows x 512 cols.
// sim bounded by 1 (cos-sim, diagonal == 1) -> softmax uses constant max 1/T:
//   p = exp((sim-1)/T), denominator >= 1 always. No running max needed.
// p kept bf16-packed in registers (64 VGPR) -> GEMM runs once, output written once.
__global__ __launch_bounds__(512) void adjmain_kernel(const unsigned short* __restrict__ hn,
                                                      const float* __restrict__ tptr,
                                                      float* __restrict__ out) {
    const int b       = blockIdx.y;
    const int rowBase = blockIdx.x * 32;
    const int lane = threadIdx.x & 63;
    const int wid  = threadIdx.x >> 6;
    const int cq   = wid & 3;       // column quarter: cols [cq*512, cq*512+512)
    const int rh   = wid >> 2;      // row half: rows [rh*16, rh*16+16) of the strip
    const int l15  = lane & 15;
    const int g    = lane >> 4;     // k-chunk (inputs) / row-quad (output)

    const float invt = 1.0f / tptr[0];

    const unsigned short* Hb = hn + (size_t)b * NN * ND;

    // A fragments for this wave's 16 rows, full K=128 (4 chunks of 32)
    short8 afrag[4];
    {
        const unsigned short* ap = Hb + (size_t)(rowBase + rh * 16 + l15) * ND + g * 8;
        #pragma unroll
        for (int c = 0; c < 4; ++c)
            afrag[c] = *reinterpret_cast<const short8*>(ap + c * 32);
    }

    const int colBase = cq * 512;
    float rs[4] = {0.f, 0.f, 0.f, 0.f};
    uint32_t pp[32][2];             // bf16-packed p, fully-unrolled static indexing

    #pragma unroll
    for (int t = 0; t < 32; ++t) {
        const unsigned short* bp = Hb + (size_t)(colBase + t * 16 + l15) * ND + g * 8;
        f32x4 acc = {0.f, 0.f, 0.f, 0.f};
        #pragma unroll
        for (int c = 0; c < 4; ++c) {
            const short8 bfrag = *reinterpret_cast<const short8*>(bp + c * 32);
            acc = __builtin_amdgcn_mfma_f32_16x16x32_bf16(afrag[c], bfrag, acc, 0, 0, 0);
        }
        // C/D layout (m89): col = lane&15, row = (lane>>4)*4 + reg
        const float p0 = __expf((acc[0] - 1.0f) * invt);
        const float p1 = __expf((acc[1] - 1.0f) * invt);
        const float p2 = __expf((acc[2] - 1.0f) * invt);
        const float p3 = __expf((acc[3] - 1.0f) * invt);
        rs[0] += p0; rs[1] += p1; rs[2] += p2; rs[3] += p3;
        pp[t][0] = pack_bf16(p0, p1);
        pp[t][1] = pack_bf16(p2, p3);
    }

    // Row-sum reduce across the 16 lanes of each group (they hold different cols)
    #pragma unroll
    for (int r = 0; r < 4; ++r) {
        #pragma unroll
        for (int m = 1; m < 16; m <<= 1) rs[r] += __shfl_xor(rs[r], m);
    }

    // Cross-wave: the 4 column-quarter waves of each row-half share rows
    __shared__ float rsum_lds[2][4][16];
    if (l15 == 0) {
        #pragma unroll
        for (int r = 0; r < 4; ++r) rsum_lds[rh][cq][g * 4 + r] = rs[r];
    }
    __syncthreads();
    float invs[4];
    #pragma unroll
    for (int r = 0; r < 4; ++r) {
        const int rr = g * 4 + r;
        const float s = rsum_lds[rh][0][rr] + rsum_lds[rh][1][rr] +
                        rsum_lds[rh][2][rr] + rsum_lds[rh][3][rr];
        invs[r] = 1.0f / s;
    }

    // Phase 2: scale and store (row = rowBase + rh*16 + g*4 + r, col = colBase + t*16 + l15)
    float* orow = out + ((size_t)b * NN + rowBase + rh * 16 + g * 4) * NN + colBase + l15;
    #pragma unroll
    for (int t = 0; t < 32; ++t) {
        const int co = t * 16;
        orow[(size_t)0 * NN + co] = unpk_lo(pp[t][0]) * invs[0];
        orow[(size_t)1 * NN + co] = unpk_hi(pp[t][0]) * invs[1];
        orow[(size_t)2 * NN + co] = unpk_lo(pp[t][1]) * invs[2];
        orow[(size_t)3 * NN + co] = unpk_hi(pp[t][1]) * invs[3];
    }
}

extern "C" void kernel_launch(void* const* d_in, const int* in_sizes, int n_in,
                              void* d_out, int out_size, void* d_ws, size_t ws_size,
                              hipStream_t stream) {
    const float* h  = (const float*)d_in[0];
    const float* tp = (const float*)d_in[1];
    unsigned short* hn = (unsigned short*)d_ws;     // 8*2048*128*2 = 4 MB of ws
    float* out = (float*)d_out;

    hipLaunchKernelGGL(adjnorm_kernel, dim3(NB * NN / 4), dim3(256), 0, stream, h, hn);
    hipLaunchKernelGGL(adjmain_kernel, dim3(NN / 32, NB), dim3(512), 0, stream, hn, tp, out);
}

// Round 4
// 197.896 us; speedup vs baseline: 1.0260x; 1.0260x over previous
//
#include <hip/hip_runtime.h>
#include <hip/hip_bf16.h>
#include <stdint.h>

// Problem dims (fixed by reference): h [8, 2048, 128] fp32 -> adj [8, 2048, 2048] fp32
#define NB 8
#define NN 2048
#define ND 128

typedef __attribute__((ext_vector_type(8))) short short8;   // 8 bf16 = 4 VGPR (MFMA A/B frag)
typedef __attribute__((ext_vector_type(4))) float f32x4;    // MFMA C/D frag

__device__ __forceinline__ uint32_t pack_bf16(float a, float b) {
    unsigned short ua = __builtin_bit_cast(unsigned short, __float2bfloat16(a));
    unsigned short ub = __builtin_bit_cast(unsigned short, __float2bfloat16(b));
    return (uint32_t)ua | ((uint32_t)ub << 16);
}
__device__ __forceinline__ float unpk_lo(uint32_t p) { return __builtin_bit_cast(float, p << 16); }
__device__ __forceinline__ float unpk_hi(uint32_t p) { return __builtin_bit_cast(float, p & 0xffff0000u); }

// Kernel 1: fp32 row-normalize -> bf16 hn in workspace.
__global__ __launch_bounds__(256) void adjnorm_kernel(const float* __restrict__ h,
                                                      unsigned short* __restrict__ hn) {
    const int row  = blockIdx.x * 4 + (threadIdx.x >> 6);
    const int lane = threadIdx.x & 63;
    const float2 v = reinterpret_cast<const float2*>(h + (size_t)row * ND)[lane];
    float ss = v.x * v.x + v.y * v.y;
    #pragma unroll
    for (int m = 32; m >= 1; m >>= 1) ss += __shfl_xor(ss, m);
    const float nrm = fmaxf(sqrtf(ss), 1e-8f);   // torch cosine_similarity eps
    const float inv = 1.0f / nrm;
    reinterpret_cast<uint32_t*>(hn + (size_t)row * ND)[lane] = pack_bf16(v.x * inv, v.y * inv);
}

// Kernel 2: fused sim-GEMM + softmax.
// Block = 8 waves = 512 thr, owns 16 rows x 2048 cols of one batch.
// Wave w: 16 rows x 256 cols (16 tiles of 16x16), pp[16][2] bf16-packed in regs.
// sim bounded by 1 (cos-sim, diag == 1) -> constant softmax max 1/T, no running max.
// B fragments software-prefetched 1-deep (ping-pong bA/bB) to hide L2 latency;
// VGPR budget deliberately ~105 (occupancy steps at 128, so prefetch regs are free).
__global__ __launch_bounds__(512) void adjmain_kernel(const unsigned short* __restrict__ hn,
                                                      const float* __restrict__ tptr,
                                                      float* __restrict__ out) {
    const int b       = blockIdx.y;
    const int rowBase = blockIdx.x * 16;
    const int lane = threadIdx.x & 63;
    const int w    = threadIdx.x >> 6;   // wave id -> column slice [w*256, w*256+256)
    const int l15  = lane & 15;
    const int g    = lane >> 4;          // k-chunk (inputs) / row-quad (output)

    const float invt = 1.0f / tptr[0];

    const unsigned short* Hb = hn + (size_t)b * NN * ND;

    // A fragments: this block's 16 rows, full K=128 (4 chunks of 32)
    short8 afrag[4];
    {
        const unsigned short* ap = Hb + (size_t)(rowBase + l15) * ND + g * 8;
        #pragma unroll
        for (int c = 0; c < 4; ++c)
            afrag[c] = *reinterpret_cast<const short8*>(ap + c * 32);
    }

    const unsigned short* colPtr = Hb + (size_t)(w * 256 + l15) * ND + g * 8;

    float rs[4] = {0.f, 0.f, 0.f, 0.f};
    uint32_t pp[16][2];                  // bf16-packed p, static indexing only
    short8 bA[4], bB[4];                 // ping-pong prefetch buffers

#define LOADB(dst, T) do {                                                      \
        const unsigned short* _bp = colPtr + (size_t)(T) * 16 * ND;             \
        dst[0] = *reinterpret_cast<const short8*>(_bp);                         \
        dst[1] = *reinterpret_cast<const short8*>(_bp + 32);                    \
        dst[2] = *reinterpret_cast<const short8*>(_bp + 64);                    \
        dst[3] = *reinterpret_cast<const short8*>(_bp + 96);                    \
    } while (0)

#define COMPUTE(T, BUF) do {                                                    \
        f32x4 acc = {0.f, 0.f, 0.f, 0.f};                                       \
        acc = __builtin_amdgcn_mfma_f32_16x16x32_bf16(afrag[0], BUF[0], acc, 0, 0, 0); \
        acc = __builtin_amdgcn_mfma_f32_16x16x32_bf16(afrag[1], BUF[1], acc, 0, 0, 0); \
        acc = __builtin_amdgcn_mfma_f32_16x16x32_bf16(afrag[2], BUF[2], acc, 0, 0, 0); \
        acc = __builtin_amdgcn_mfma_f32_16x16x32_bf16(afrag[3], BUF[3], acc, 0, 0, 0); \
        const float p0 = __expf((acc[0] - 1.0f) * invt);                        \
        const float p1 = __expf((acc[1] - 1.0f) * invt);                        \
        const float p2 = __expf((acc[2] - 1.0f) * invt);                        \
        const float p3 = __expf((acc[3] - 1.0f) * invt);                        \
        rs[0] += p0; rs[1] += p1; rs[2] += p2; rs[3] += p3;                     \
        pp[T][0] = pack_bf16(p0, p1);                                           \
        pp[T][1] = pack_bf16(p2, p3);                                           \
    } while (0)

    LOADB(bA, 0);
    #pragma unroll
    for (int tt = 0; tt < 8; ++tt) {
        LOADB(bB, 2 * tt + 1);           // prefetch odd tile before computing even
        COMPUTE(2 * tt, bA);
        if (tt < 7) LOADB(bA, 2 * tt + 2); // prefetch next even before computing odd
        COMPUTE(2 * tt + 1, bB);
    }
#undef LOADB
#undef COMPUTE

    // Row-sum reduce across the 16 lanes of each g-group (they hold different cols)
    #pragma unroll
    for (int r = 0; r < 4; ++r) {
        #pragma unroll
        for (int m = 1; m < 16; m <<= 1) rs[r] += __shfl_xor(rs[r], m);
    }

    // Cross-wave reduce: all 8 waves cover different column slices of the same 16 rows
    __shared__ float rsum_lds[8][16];
    if (l15 == 0) {
        #pragma unroll
        for (int r = 0; r < 4; ++r) rsum_lds[w][g * 4 + r] = rs[r];
    }
    __syncthreads();
    float invs[4];
    #pragma unroll
    for (int r = 0; r < 4; ++r) {
        const int rr = g * 4 + r;
        float s = 0.f;
        #pragma unroll
        for (int ww = 0; ww < 8; ++ww) s += rsum_lds[ww][rr];
        invs[r] = 1.0f / s;
    }

    // Phase 2: scale and store. row = rowBase + g*4 + r, col = w*256 + t*16 + l15
    float* orow = out + ((size_t)b * NN + rowBase + g * 4) * NN + w * 256 + l15;
    #pragma unroll
    for (int t = 0; t < 16; ++t) {
        const int co = t * 16;
        orow[(size_t)0 * NN + co] = unpk_lo(pp[t][0]) * invs[0];
        orow[(size_t)1 * NN + co] = unpk_hi(pp[t][0]) * invs[1];
        orow[(size_t)2 * NN + co] = unpk_lo(pp[t][1]) * invs[2];
        orow[(size_t)3 * NN + co] = unpk_hi(pp[t][1]) * invs[3];
    }
}

extern "C" void kernel_launch(void* const* d_in, const int* in_sizes, int n_in,
                              void* d_out, int out_size, void* d_ws, size_t ws_size,
                              hipStream_t stream) {
    const float* h  = (const float*)d_in[0];
    const float* tp = (const float*)d_in[1];
    unsigned short* hn = (unsigned short*)d_ws;     // 8*2048*128*2 = 4 MB of ws
    float* out = (float*)d_out;

    hipLaunchKernelGGL(adjnorm_kernel, dim3(NB * NN / 4), dim3(256), 0, stream, h, hn);
    hipLaunchKernelGGL(adjmain_kernel, dim3(NN / 16, NB), dim3(512), 0, stream, hn, tp, out);
}